// Round 4
// baseline (384.511 us; speedup 1.0000x reference)
//
#include <hip/hip_runtime.h>
#include <math.h>

#define NB    2048
#define NSEG  20
#define MAXIT 48

typedef __attribute__((ext_vector_type(8))) short bf8_t;
typedef __attribute__((ext_vector_type(4))) float f32x4;

#define cA21 ((float)0.161)
#define cA31 ((float)-0.008480655492356989)
#define cA32 ((float)0.335480655492357)
#define cA41 ((float)2.8971530571054935)
#define cA42 ((float)-6.359448489975075)
#define cA43 ((float)4.3622954328695815)
#define cA51 ((float)5.325864828439257)
#define cA52 ((float)-11.748883564062828)
#define cA53 ((float)7.4955393428898365)
#define cA54 ((float)-0.09249506636175525)
#define cA61 ((float)5.86145544294642)
#define cA62 ((float)-12.92096931784711)
#define cA63 ((float)8.159367898576159)
#define cA64 ((float)-0.071584973281401)
#define cA65 ((float)-0.028269050394068383)
#define cB1  ((float)0.09646076681806523)
#define cB2  ((float)0.01)
#define cB3  ((float)0.4798896504144996)
#define cB4  ((float)1.379008574103742)
#define cB5  ((float)-3.290069515436081)
#define cB6  ((float)2.324710524099774)
#define cE1  ((float)-0.001780011052225777)
#define cE2  ((float)-0.0008164344596567469)
#define cE3  ((float)0.007880878010261995)
#define cE4  ((float)-0.1447110071732629)
#define cE5  ((float)0.5823571654525552)
#define cE6  ((float)-0.45808210592918697)
#define cE7  ((float)0.015151515151515152)

__device__ __forceinline__ void split2(float x, short &hi, short &lo) {
    unsigned u = __float_as_uint(x);
    hi = (short)(u >> 16);
    float r = x - __uint_as_float(u & 0xFFFF0000u);
    lo = (short)(__float_as_uint(r) >> 16);
}

__device__ __forceinline__ float softplus_f(float x) {
    float t = exp2f(-fabsf(x) * 1.442695040888963f);
    return fmaxf(x, 0.0f) + log2f(1.0f + t) * 0.6931471805599453f;
}

__device__ __forceinline__ unsigned pk(short a, short b) {
    return ((unsigned)(unsigned short)a) | (((unsigned)(unsigned short)b) << 16);
}

__device__ __forceinline__ float sx8(float v) { return __shfl_xor(v, 8, 64); }

// 512 threads = 8 waves; 8 elements per block in lockstep.
// B-operand (acts): element e hi at col e, lo at col e+8 -> 1 read + 2 MFMA/chunk.
// ODE state (y, k1..k6, t, dt) lives in MFMA C-layout on waves 0-3:
//   lane (quad,col<8) holds rows jb..jb+3 (d-dims) of element col.
__global__ __launch_bounds__(512)
void ode_kernel(const float* __restrict__ history,
                const float* __restrict__ W1, const float* __restrict__ b1,
                const float* __restrict__ W2, const float* __restrict__ b2,
                const float* __restrict__ W3, const float* __restrict__ b3,
                float* __restrict__ out)
{
    // chunk = 4 quads * (16 cols * 8 + 8 pad) = 544 shorts
    __shared__ alignas(16) short argC[2 * 544];
    __shared__ alignas(16) short h1C[4 * 544];
    __shared__ alignas(16) short h2C[4 * 544];
    __shared__ float partS[32];

    const int tid  = threadIdx.x;
    const int wave = tid >> 6, lane = tid & 63;
    const int quad = lane >> 4, col = lane & 15;
    const int jb   = 16 * wave + 4 * quad;        // this lane's D-row base
    const bool w03  = (wave < 4);
    const bool real = w03 && (col < 8);

    // ---- weight A-fragments (bf16 hi/lo), layout verified in round 3 ----
    bf8_t A1h[2], A1l[2], A2h[4], A2l[4], A3h[4], A3l[4];
#pragma unroll
    for (int c = 0; c < 2; ++c) {
        const float* p = W1 + (size_t)(16 * wave + col) * 64 + 32 * c + 8 * quad;
        bf8_t h, l;
#pragma unroll
        for (int j = 0; j < 8; ++j) { short hs, ls; split2(p[j], hs, ls); h[j] = hs; l[j] = ls; }
        A1h[c] = h; A1l[c] = l;
    }
#pragma unroll
    for (int c = 0; c < 4; ++c) {
        const float* p = W2 + (size_t)(16 * wave + col) * 128 + 32 * c + 8 * quad;
        bf8_t h, l;
#pragma unroll
        for (int j = 0; j < 8; ++j) { short hs, ls; split2(p[j], hs, ls); h[j] = hs; l[j] = ls; }
        A2h[c] = h; A2l[c] = l;
    }
    f32x4 b3f = {0.f, 0.f, 0.f, 0.f};
    if (w03) {
#pragma unroll
        for (int c = 0; c < 4; ++c) {
            const float* p = W3 + (size_t)(16 * wave + col) * 128 + 32 * c + 8 * quad;
            bf8_t h, l;
#pragma unroll
            for (int j = 0; j < 8; ++j) { short hs, ls; split2(p[j], hs, ls); h[j] = hs; l[j] = ls; }
            A3h[c] = h; A3l[c] = l;
        }
        b3f = *(const f32x4*)(b3 + jb);
    } else {
        bf8_t z = {0, 0, 0, 0, 0, 0, 0, 0};
#pragma unroll
        for (int c = 0; c < 4; ++c) { A3h[c] = z; A3l[c] = z; }
    }
    const f32x4 b1f = *(const f32x4*)(b1 + jb);
    const f32x4 b2f = *(const f32x4*)(b2 + jb);

    // row-base LDS index for writes from C-layout (4 consecutive k at fixed n)
    const int wIdx = (jb >> 5) * 544 + ((jb >> 3) & 3) * 136 + (jb & 7);

    // D = Ah*B (hh | h*l) and Al*B (lh | ll); combine for cols<8
    auto gemm2 = [&](const bf8_t* Ah, const bf8_t* Al, const short* B, int nch) -> f32x4 {
        bf8_t bf[4];
#pragma unroll 4
        for (int c = 0; c < nch; ++c)
            bf[c] = *(const bf8_t*)(B + c * 544 + quad * 136 + col * 8);
        f32x4 d1 = {0.f, 0.f, 0.f, 0.f}, d2 = {0.f, 0.f, 0.f, 0.f};
#pragma unroll 4
        for (int c = 0; c < nch; ++c) {
            d1 = __builtin_amdgcn_mfma_f32_16x16x32_bf16(Ah[c], bf[c], d1, 0, 0, 0);
            d2 = __builtin_amdgcn_mfma_f32_16x16x32_bf16(Al[c], bf[c], d2, 0, 0, 0);
        }
        f32x4 o;
#pragma unroll
        for (int r = 0; r < 4; ++r) o[r] = d1[r] + sx8(d1[r]) + d2[r];
        return o;
    };

    // softplus + split + write hi/lo B-fragments (cols<8 lanes only)
    auto epiwr = [&](f32x4 pre, f32x4 bias, short* H) {
        if (col < 8) {
            short hh[4], ll[4];
#pragma unroll
            for (int r = 0; r < 4; ++r) {
                float v = softplus_f(pre[r] + bias[r]);
                split2(v, hh[r], ll[r]);
            }
            *(uint2*)(H + wIdx + col * 8)       = make_uint2(pk(hh[0], hh[1]), pk(hh[2], hh[3]));
            *(uint2*)(H + wIdx + (col + 8) * 8) = make_uint2(pk(ll[0], ll[1]), pk(ll[2], ll[3]));
        }
    };

    // write stage argument from C-layout (waves 0-3, cols<8)
    auto writeArg = [&](f32x4 a) {
        if (real) {
            short hh[4], ll[4];
#pragma unroll
            for (int r = 0; r < 4; ++r) split2(a[r], hh[r], ll[r]);
            *(uint2*)(argC + wIdx + col * 8)       = make_uint2(pk(hh[0], hh[1]), pk(hh[2], hh[3]));
            *(uint2*)(argC + wIdx + (col + 8) * 8) = make_uint2(pk(ll[0], ll[1]), pk(ll[2], ll[3]));
        }
    };

    // full MLP eval; argC must be written. Returns k (valid on waves 0-3, cols<8).
    auto evalK = [&]() -> f32x4 {
        __syncthreads();
        f32x4 p1 = gemm2(A1h, A1l, argC, 2);
        epiwr(p1, b1f, h1C);
        __syncthreads();
        f32x4 p2 = gemm2(A2h, A2l, h1C, 4);
        epiwr(p2, b2f, h2C);
        __syncthreads();
        f32x4 kv = {0.f, 0.f, 0.f, 0.f};
        if (w03) {
            f32x4 p3 = gemm2(A3h, A3l, h2C, 4);
#pragma unroll
            for (int r = 0; r < 4; ++r) kv[r] = p3[r] + b3f[r];
        }
        return kv;
    };

    // ---- init state (C-layout) ----
    const int eb = blockIdx.x * 8;
    f32x4 y = {0.f, 0.f, 0.f, 0.f};
    if (real)
        y = *(const f32x4*)(history + ((size_t)(eb + col) * 15 + 14) * 64 + jb);
    float dt = 0.1f;
    float t = 0.f;
    f32x4 k1, k2, k3, k4, k5, k6;

    writeArg(y);
    k1 = evalK();   // FSAL seed

#pragma unroll 1
    for (int seg = 1; seg <= NSEG; ++seg) {
        const float t1 = (float)seg;
        t = t1 - 1.0f;
        bool done = false;

#pragma unroll 1
        for (int it = 0; it < MAXIT; ++it) {
            const float dt_c = fminf(dt, t1 - t);
            const float h = dt_c;
            f32x4 y5 = {0.f, 0.f, 0.f, 0.f}, k7 = {0.f, 0.f, 0.f, 0.f};

#pragma unroll 1
            for (int st = 2; st <= 7; ++st) {
                f32x4 a;
#pragma unroll
                for (int r = 0; r < 4; ++r) {
                    float sum;
                    switch (st) {
                        case 2: sum = cA21 * k1[r]; break;
                        case 3: sum = fmaf(cA31, k1[r], cA32 * k2[r]); break;
                        case 4: sum = fmaf(cA41, k1[r], fmaf(cA42, k2[r], cA43 * k3[r])); break;
                        case 5: sum = fmaf(cA51, k1[r], fmaf(cA52, k2[r], fmaf(cA53, k3[r], cA54 * k4[r]))); break;
                        case 6: sum = fmaf(cA61, k1[r], fmaf(cA62, k2[r], fmaf(cA63, k3[r], fmaf(cA64, k4[r], cA65 * k5[r])))); break;
                        default: sum = fmaf(cB1, k1[r], fmaf(cB2, k2[r], fmaf(cB3, k3[r], fmaf(cB4, k4[r], fmaf(cB5, k5[r], cB6 * k6[r]))))); break;
                    }
                    a[r] = fmaf(h, sum, y[r]);
                }
                if (st == 7) y5 = a;
                writeArg(a);
                f32x4 kv = evalK();
                switch (st) {
                    case 2: k2 = kv; break;
                    case 3: k3 = kv; break;
                    case 4: k4 = kv; break;
                    case 5: k5 = kv; break;
                    case 6: k6 = kv; break;
                    default: k7 = kv; break;
                }
            }

            // err norm: per-lane over 4 rows, quad-shuffles, cross-wave LDS partials
            float rr = 0.f;
            if (real) {
#pragma unroll
                for (int r = 0; r < 4; ++r) {
                    float es = fmaf(cE1, k1[r], fmaf(cE2, k2[r], fmaf(cE3, k3[r],
                               fmaf(cE4, k4[r], fmaf(cE5, k5[r], fmaf(cE6, k6[r], cE7 * k7[r]))))));
                    float e = h * es;
                    float sc = fmaf(1e-3f, fmaxf(fabsf(y[r]), fabsf(y5[r])), 1e-6f);
                    float q = e / sc;
                    rr = fmaf(q, q, rr);
                }
            }
            rr += __shfl_xor(rr, 16, 64);
            rr += __shfl_xor(rr, 32, 64);
            if (real && quad == 0) partS[wave * 8 + col] = rr;
            __syncthreads();

            float en = 0.f;
            if (w03) {
                int cc = col & 7;
                en = sqrtf((partS[cc] + partS[8 + cc] + partS[16 + cc] + partS[24 + cc])
                           * (1.0f / 64.0f));
            }
            bool accept = (en <= 1.0f) && !done;
            float fac = 0.9f * exp2f(-0.2f * log2f(fmaxf(en, 1e-10f)));
            fac = fminf(fmaxf(fac, 0.2f), 10.0f);

            if (accept) { t += dt_c; y = y5; k1 = k7; }   // FSAL
            if (!done) dt = dt_c * fac;
            done = done || (t >= t1 - 1e-8f);

            int my = real ? (done ? 1 : 0) : 1;
            if (__syncthreads_and(my)) break;
        }

        if (real)
            *(f32x4*)(out + ((size_t)(eb + col) * NSEG + (seg - 1)) * 64 + jb) = y;
    }
}

extern "C" void kernel_launch(void* const* d_in, const int* in_sizes, int n_in,
                              void* d_out, int out_size, void* d_ws, size_t ws_size,
                              hipStream_t stream) {
    const float* history = (const float*)d_in[0];
    const float* W1 = (const float*)d_in[1];
    const float* b1 = (const float*)d_in[2];
    const float* W2 = (const float*)d_in[3];
    const float* b2 = (const float*)d_in[4];
    const float* W3 = (const float*)d_in[5];
    const float* b3 = (const float*)d_in[6];
    float* out = (float*)d_out;

    ode_kernel<<<dim3(NB / 8), dim3(512), 0, stream>>>(history, W1, b1, W2, b2, W3, b3, out);
}